// Round 20
// baseline (245.380 us; speedup 1.0000x reference)
//
#include <hip/hip_runtime.h>
#include <hip/hip_bf16.h>

#define NSESS 2048
#define NI 64      // I
#define LL 63      // L = I-1
#define EE 256
#define HH 128
#define GG 384     // 3H

typedef __attribute__((ext_vector_type(8))) short short8;
typedef __attribute__((ext_vector_type(4))) float f32x4;

static __device__ __forceinline__ unsigned short f2b(float f) {
  union { float f; unsigned u; } v; v.f = f;
  unsigned r = (v.u + 0x7FFFu + ((v.u >> 16) & 1u)) >> 16;
  return (unsigned short)r;
}
static __device__ __forceinline__ float b2f(unsigned short s) {
  union { unsigned u; float f; } v; v.u = ((unsigned)s) << 16;
  return v.f;
}
static __device__ __forceinline__ float lo16(unsigned u) {
  union { unsigned v; float f; } x; x.v = u << 16; return x.f;
}
static __device__ __forceinline__ float hi16(unsigned u) {
  union { unsigned v; float f; } x; x.v = u & 0xFFFF0000u; return x.f;
}
static __device__ __forceinline__ float sigmoidf_(float x) {
  return 1.f / (1.f + __expf(-x));
}
static __device__ __forceinline__ float tanh2_(float y) {
  float e = __expf(2.f * y);            // inf-safe
  return 1.f - 2.f / (1.f + e);
}
// LDS-only barrier: waits ds ops, does NOT drain vmcnt.
static __device__ __forceinline__ void barrier_lds_only() {
  asm volatile("s_waitcnt lgkmcnt(0)" ::: "memory");
  __builtin_amdgcn_sched_barrier(0);
  __builtin_amdgcn_s_barrier();
  __builtin_amdgcn_sched_barrier(0);
}

// ---------------- K1: per-session prep ----------------
__global__ __launch_bounds__(64) void prep_kernel(const int* __restrict__ item_id,
                                                  const int* __restrict__ eval_from,
                                                  const int* __restrict__ u_type,
                                                  int* __restrict__ len_in,
                                                  int* __restrict__ inp,
                                                  float* __restrict__ out) {
  int n = blockIdx.x;          // session
  int lane = threadIdx.x;      // 0..63
  int b = n >> 5, s = n & 31;
  int allow = (s >= eval_from[b]) ? 1 : 0;
  int id = item_id[n * NI + lane];
  if (id < 0) id = 0;
  id *= allow;
  unsigned long long m = __ballot(id != 0);
  int length = __popcll(m);
  int li = length - 1;
  int tv = __shfl(id, (length > 0) ? (length - 1) : 0, 64);
  int target = (length > 0) ? tv : 0;
  if (lane < LL) inp[n * LL + lane] = (lane < li) ? id : 0;
  if (lane == 0) {
    len_in[n] = li;
    out[NSESS * 256 + n] = (float)target;            // Output 1: target
    out[NSESS * 256 + NSESS + n] = (float)u_type[b]; // Output 2: u
  }
}

// ---------------- K2: weights -> bf16 ----------------
__global__ __launch_bounds__(256) void cvt_weights(const float* __restrict__ W_ih,
                                                   const float* __restrict__ W_hh,
                                                   const float* __restrict__ W_a1,
                                                   unsigned short* __restrict__ Wb,
                                                   unsigned short* __restrict__ Whs,
                                                   unsigned short* __restrict__ Wa1b) {
  int i = blockIdx.x * 256 + threadIdx.x;   // 98304 threads
  Wb[i] = f2b(W_ih[i]);
  if (i < GG * HH) Whs[i] = f2b(W_hh[i]);   // W_hh bf16 [384][128]
  if (i < HH * HH) Wa1b[i] = f2b(W_a1[i]);  // W_a1 bf16 [N][K]
}

// ---------------- K3: gi = emb[inp] @ W_ih^T + b_ih  (wave-independent) ----------------
// 2016 blocks x 256 thr (4 waves). Wave J = blockIdx*4+w: gate strip (J&7)*48
// (B register-resident), M-tiles (J>>3)*8 .. +7. A direct emb->reg (16 float4
// batch-issued, convert+MFMA per chunk). NO LDS, NO barriers. gi: [l][n][384].
__global__ __launch_bounds__(256, 2) void gemm_in(const float* __restrict__ emb,
                                                  const unsigned short* __restrict__ Wb,
                                                  const float* __restrict__ b_ih,
                                                  const int* __restrict__ inp,
                                                  unsigned short* __restrict__ gi) {
  const int t = threadIdx.x;
  const int lane = t & 63, w = t >> 6;
  const int ccol = lane & 15, kg = lane >> 4;
  const long J = (long)blockIdx.x * 4 + w;     // 0..8063
  const int g0 = (int)(J & 7) * 48;
  const int mbase = (int)(J >> 3) * 8;

  // B fragments: gates g0..g0+47, full K=256 (96 VGPR)
  short8 bfr[3][8];
#pragma unroll
  for (int nt = 0; nt < 3; ++nt) {
    const unsigned short* wrow = Wb + (long)(g0 + nt * 16 + ccol) * EE + kg * 8;
#pragma unroll
    for (int c = 0; c < 8; ++c) bfr[nt][c] = *(const short8*)(wrow + c * 32);
  }
  float bias[3];
#pragma unroll
  for (int nt = 0; nt < 3; ++nt) bias[nt] = b_ih[g0 + nt * 16 + ccol];

  for (int i = 0; i < 8; ++i) {
    const int m = mbase + i;
    long rid = inp[m * 16 + ccol];
    const float* xrow = emb + rid * EE + kg * 8;

    // batch-issue all 16 A loads (compiler pipelines; waits inserted per use)
    float4 L[16];
#pragma unroll
    for (int c = 0; c < 8; ++c) {
      L[2 * c]     = *(const float4*)(xrow + c * 32);
      L[2 * c + 1] = *(const float4*)(xrow + c * 32 + 4);
    }

    f32x4 acc[3];
#pragma unroll
    for (int nt = 0; nt < 3; ++nt)
      acc[nt] = (f32x4){bias[nt], bias[nt], bias[nt], bias[nt]};

#pragma unroll
    for (int c = 0; c < 8; ++c) {
      short8 af;
      af[0] = (short)f2b(L[2 * c].x);     af[1] = (short)f2b(L[2 * c].y);
      af[2] = (short)f2b(L[2 * c].z);     af[3] = (short)f2b(L[2 * c].w);
      af[4] = (short)f2b(L[2 * c + 1].x); af[5] = (short)f2b(L[2 * c + 1].y);
      af[6] = (short)f2b(L[2 * c + 1].z); af[7] = (short)f2b(L[2 * c + 1].w);
#pragma unroll
      for (int nt = 0; nt < 3; ++nt)
        acc[nt] = __builtin_amdgcn_mfma_f32_16x16x32_bf16(af, bfr[nt][c], acc[nt], 0, 0, 0);
    }

    // store: row mrow = m*16 + kg*4 + j -> (n = mrow/63, l = mrow%63); gi[l][n][g]
    long base[4];
#pragma unroll
    for (int j = 0; j < 4; ++j) {
      int mrow = m * 16 + kg * 4 + j;
      int n = mrow / 63;
      int l = mrow - 63 * n;
      base[j] = ((long)l * NSESS + n) * GG;
    }
#pragma unroll
    for (int nt = 0; nt < 3; ++nt) {
      int g = g0 + nt * 16 + ccol;
#pragma unroll
      for (int j = 0; j < 4; ++j)
        gi[base[j] + g] = f2b(acc[nt][j]);
    }
  }
}

// ---------------- K4: GRU via MFMA, SWAPPED operands: C[session][gate] ----------------
// 128 WGs x 512 thr, 16 sess/WG. mfma(A=W_hh, B=h): lane owns session=ccol,
// gate positions p0..p0+3. Per step/wave: 4 ds_read_b128 + 3 global b64 gv
// (prefetched 2 deep) + 12 MFMA + gates + 1 ds_write_b64 + 1 global b64 store.
__global__ __launch_bounds__(512) void gru_mfma(const unsigned short* __restrict__ Whs,
                                                const float* __restrict__ b_hh,
                                                const unsigned short* __restrict__ gi,
                                                const int* __restrict__ len_in,
                                                unsigned short* __restrict__ outs,
                                                float* __restrict__ ht,
                                                float* __restrict__ out) {
  __shared__ unsigned short ring[2 * 2048];   // 8192 B: [slot][16 sess][128] swz16B

  const int t = threadIdx.x;
  const int w = t >> 6, lane = t & 63;
  const int ccol = lane & 15, kg = lane >> 4;
  const int n0 = blockIdx.x * 16;
  const int jh = w * 16 + ccol;     // A-frag row (gate within cls)
  const int p0 = w * 16 + kg * 4;   // this lane's 4 gate positions (C rows)
  const int swz = (ccol & 7) << 3;  // u16-unit XOR key

  short8 bfr[3][4];
#pragma unroll
  for (int cls = 0; cls < 3; ++cls) {
    const unsigned short* wrow = Whs + (long)(cls * HH + jh) * HH;
#pragma unroll
    for (int c = 0; c < 4; ++c)
      bfr[cls][c] = *(const short8*)(wrow + c * 32 + kg * 8);
  }
  f32x4 bhv[3];
#pragma unroll
  for (int cls = 0; cls < 3; ++cls)
    bhv[cls] = *(const f32x4*)(b_hh + cls * HH + p0);

  const int li = len_in[n0 + ccol];
  float hold[4] = {0.f, 0.f, 0.f, 0.f};

  for (int idx = t; idx < 2 * 2048; idx += 512) ring[idx] = 0;

  const unsigned short* gbase = gi + (long)(n0 + ccol) * GG + p0;
  const long lstride = (long)NSESS * GG;
#define GA(l, cls) ((const uint2*)(gbase + (long)(l) * lstride + (cls) * HH))

  uint2 gA[3], gB[3];
#pragma unroll
  for (int cls = 0; cls < 3; ++cls) gA[cls] = *GA(0, cls);
#pragma unroll
  for (int cls = 0; cls < 3; ++cls) gB[cls] = *GA(1, cls);

  barrier_lds_only();

  auto step = [&](int l, uint2 (&gbuf)[3]) {
    float gvv[3][4];
#pragma unroll
    for (int cls = 0; cls < 3; ++cls) {
      gvv[cls][0] = lo16(gbuf[cls].x); gvv[cls][1] = hi16(gbuf[cls].x);
      gvv[cls][2] = lo16(gbuf[cls].y); gvv[cls][3] = hi16(gbuf[cls].y);
    }
    if (l + 2 < LL) {
#pragma unroll
      for (int cls = 0; cls < 3; ++cls) gbuf[cls] = *GA(l + 2, cls);
    }

    const unsigned short* rb = ring + ((l + 1) & 1) * 2048 + ccol * HH;
    short8 hf[4];
#pragma unroll
    for (int c = 0; c < 4; ++c)
      hf[c] = *(const short8*)(rb + ((c * 32 + kg * 8) ^ swz));

    f32x4 acc[3];
#pragma unroll
    for (int cls = 0; cls < 3; ++cls) {
      acc[cls] = bhv[cls];
#pragma unroll
      for (int c = 0; c < 4; ++c)
        acc[cls] = __builtin_amdgcn_mfma_f32_16x16x32_bf16(bfr[cls][c], hf[c], acc[cls], 0, 0, 0);
    }

    bool valid = (l < li);
#pragma unroll
    for (int j = 0; j < 4; ++j) {
      float rg = sigmoidf_(gvv[0][j] + acc[0][j]);
      float zg = sigmoidf_(gvv[1][j] + acc[1][j]);
      float ng = tanh2_(gvv[2][j] + rg * acc[2][j]);
      float hnew = ng + zg * (hold[j] - ng);
      hold[j] = valid ? hnew : hold[j];
    }
    uint2 hp;
    hp.x = (unsigned)f2b(hold[0]) | ((unsigned)f2b(hold[1]) << 16);
    hp.y = (unsigned)f2b(hold[2]) | ((unsigned)f2b(hold[3]) << 16);
    *(uint2*)(ring + (l & 1) * 2048 + ccol * HH + (p0 ^ swz)) = hp;
    uint2 ov = valid ? hp : (uint2){0u, 0u};
    *(uint2*)(outs + ((long)(n0 + ccol) * LL + l) * HH + p0) = ov;
    barrier_lds_only();
  };

  for (int b2 = 0; b2 < 31; ++b2) {
    step(2 * b2, gA);
    step(2 * b2 + 1, gB);
  }
  step(62, gA);
#undef GA

  f32x4 hv = {hold[0], hold[1], hold[2], hold[3]};
  *(f32x4*)(ht + (long)(n0 + ccol) * HH + p0) = hv;
  *(f32x4*)(out + (long)(n0 + ccol) * 256 + HH + p0) = hv;
}

// ---------------- K5: attention via MFMA ----------------
__global__ __launch_bounds__(256) void attn(const unsigned short* __restrict__ outs,
                                            const float* __restrict__ ht,
                                            const unsigned short* __restrict__ Wa1b,
                                            const float* __restrict__ W_a2,
                                            const float* __restrict__ W_vt,
                                            const int* __restrict__ len_in,
                                            float* __restrict__ out) {
  constexpr int OP = HH + 8;               // padded row stride (u16)
  __shared__ unsigned short o_l[64 * OP];  // 17408 B
  __shared__ float q2s[HH];
  __shared__ float wvt[HH];
  __shared__ float hts[HH];
  __shared__ float aw[4][64];              // per-wave alpha partials
  __shared__ float alphas[64];

  const int n = blockIdx.x;
  const int t = threadIdx.x;
  const int lane = t & 63, wv = t >> 6;
  const int ccol = lane & 15, kg = lane >> 4;
  const int li = len_in[n];

  const unsigned* src = (const unsigned*)(outs + (long)n * LL * HH);
  for (int idx = t; idx < LL * 64; idx += 256) {
    int r = idx >> 6, c2 = idx & 63;
    ((unsigned*)(o_l + r * OP))[c2] = src[r * 64 + c2];
  }
  if (t < 64) ((unsigned*)(o_l + 63 * OP))[t] = 0;
  if (t < HH) { hts[t] = ht[(long)n * HH + t]; wvt[t] = W_vt[t]; }

  short8 bfr[2][4];
#pragma unroll
  for (int nt = 0; nt < 2; ++nt) {
    int G = wv * 32 + nt * 16 + ccol;
#pragma unroll
    for (int c = 0; c < 4; ++c)
      bfr[nt][c] = *(const short8*)(Wa1b + (long)G * HH + c * 32 + kg * 8);
  }
  __syncthreads();

  if (t < HH) {
    float a = 0.f;
    const float* w2 = W_a2 + t * HH;
    for (int k = 0; k < HH; ++k) a += hts[k] * w2[k];
    q2s[t] = a;
  }
  __syncthreads();

  f32x4 acc[4][2];
#pragma unroll
  for (int mt = 0; mt < 4; ++mt)
#pragma unroll
    for (int nt = 0; nt < 2; ++nt) acc[mt][nt] = (f32x4){0.f, 0.f, 0.f, 0.f};
#pragma unroll
  for (int mt = 0; mt < 4; ++mt) {
#pragma unroll
    for (int c = 0; c < 4; ++c) {
      short8 af = *(const short8*)(o_l + (mt * 16 + ccol) * OP + c * 32 + kg * 8);
#pragma unroll
      for (int nt = 0; nt < 2; ++nt)
        acc[mt][nt] = __builtin_amdgcn_mfma_f32_16x16x32_bf16(af, bfr[nt][c], acc[mt][nt], 0, 0, 0);
    }
  }

  float q2v[2], wvv[2];
#pragma unroll
  for (int nt = 0; nt < 2; ++nt) {
    int cg = wv * 32 + nt * 16 + ccol;
    q2v[nt] = q2s[cg]; wvv[nt] = wvt[cg];
  }
#pragma unroll
  for (int mt = 0; mt < 4; ++mt) {
    float part[4] = {0.f, 0.f, 0.f, 0.f};
#pragma unroll
    for (int nt = 0; nt < 2; ++nt)
#pragma unroll
      for (int j = 0; j < 4; ++j)
        part[j] += sigmoidf_(acc[mt][nt][j] + q2v[nt]) * wvv[nt];
#pragma unroll
    for (int j = 0; j < 4; ++j) {
#pragma unroll
      for (int off = 1; off < 16; off <<= 1)
        part[j] += __shfl_xor(part[j], off, 64);
    }
    if (ccol == 0) {
#pragma unroll
      for (int j = 0; j < 4; ++j) aw[wv][mt * 16 + kg * 4 + j] = part[j];
    }
  }
  __syncthreads();

  if (t < 64) {
    float s = aw[0][t] + aw[1][t] + aw[2][t] + aw[3][t];
    alphas[t] = (t < li) ? s : 0.f;
  }
  __syncthreads();

  if (t < HH) {
    float c = 0.f;
    for (int l = 0; l < LL; ++l) c = fmaf(alphas[l], b2f(o_l[l * OP + t]), c);
    out[(long)n * 256 + t] = c;
  }
}

extern "C" void kernel_launch(void* const* d_in, const int* in_sizes, int n_in,
                              void* d_out, int out_size, void* d_ws, size_t ws_size,
                              hipStream_t stream) {
  (void)in_sizes; (void)n_in; (void)out_size; (void)ws_size;
  const int* item_id   = (const int*)d_in[0];
  const int* eval_from = (const int*)d_in[1];
  const int* u_type    = (const int*)d_in[2];
  const float* emb     = (const float*)d_in[3];
  const float* W_ih    = (const float*)d_in[4];
  const float* W_hh    = (const float*)d_in[5];
  const float* b_ih    = (const float*)d_in[6];
  const float* b_hh    = (const float*)d_in[7];
  const float* W_a1    = (const float*)d_in[8];
  const float* W_a2    = (const float*)d_in[9];
  const float* W_vt    = (const float*)d_in[10];

  float* out = (float*)d_out;   // f32: reps[2048*256] | target[2048] | u[2048]
  char* ws = (char*)d_ws;
  int* len_in           = (int*)(ws + 0);                      //      8192 B
  int* inp              = (int*)(ws + 8192);                   //    516096 B
  unsigned short* Wb    = (unsigned short*)(ws + 524288);      //    196608 B
  unsigned short* Whs   = (unsigned short*)(ws + 720896);      //     98304 B
  float* ht             = (float*)(ws + 819200);               //   1048576 B
  unsigned short* gi    = (unsigned short*)(ws + 1867776);     //  99090432 B  [l][n][384]
  unsigned short* outs  = (unsigned short*)(ws + 100958208);   //  33030144 B -> ends 133988352
  unsigned short* Wa1b  = (unsigned short*)(ws + 133988352);   //     32768 B -> ends 134021120

  prep_kernel<<<NSESS, 64, 0, stream>>>(item_id, eval_from, u_type, len_in, inp, out);
  cvt_weights<<<384, 256, 0, stream>>>(W_ih, W_hh, W_a1, Wb, Whs, Wa1b);
  gemm_in<<<2016, 256, 0, stream>>>(emb, Wb, b_ih, inp, gi);
  gru_mfma<<<NSESS / 16, 512, 0, stream>>>(Whs, b_hh, gi, len_in, outs, ht, out);
  attn<<<NSESS, 256, 0, stream>>>(outs, ht, Wa1b, W_a2, W_vt, len_in, out);
}

// Round 21
// 197.644 us; speedup vs baseline: 1.2415x; 1.2415x over previous
//
#include <hip/hip_runtime.h>
#include <hip/hip_bf16.h>

#define NSESS 2048
#define NI 64      // I
#define LL 63      // L = I-1
#define EE 256
#define HH 128
#define GG 384     // 3H

typedef __attribute__((ext_vector_type(8))) short short8;
typedef __attribute__((ext_vector_type(4))) float f32x4;

static __device__ __forceinline__ unsigned short f2b(float f) {
  union { float f; unsigned u; } v; v.f = f;
  unsigned r = (v.u + 0x7FFFu + ((v.u >> 16) & 1u)) >> 16;
  return (unsigned short)r;
}
static __device__ __forceinline__ float b2f(unsigned short s) {
  union { unsigned u; float f; } v; v.u = ((unsigned)s) << 16;
  return v.f;
}
static __device__ __forceinline__ float lo16(unsigned u) {
  union { unsigned v; float f; } x; x.v = u << 16; return x.f;
}
static __device__ __forceinline__ float hi16(unsigned u) {
  union { unsigned v; float f; } x; x.v = u & 0xFFFF0000u; return x.f;
}
static __device__ __forceinline__ float sigmoidf_(float x) {
  return 1.f / (1.f + __expf(-x));
}
static __device__ __forceinline__ float tanh2_(float y) {
  float e = __expf(2.f * y);            // inf-safe
  return 1.f - 2.f / (1.f + e);
}
// LDS-only barrier: waits ds ops, does NOT drain vmcnt.
static __device__ __forceinline__ void barrier_lds_only() {
  asm volatile("s_waitcnt lgkmcnt(0)" ::: "memory");
  __builtin_amdgcn_sched_barrier(0);
  __builtin_amdgcn_s_barrier();
  __builtin_amdgcn_sched_barrier(0);
}

// ---------------- K1: per-session prep ----------------
__global__ __launch_bounds__(64) void prep_kernel(const int* __restrict__ item_id,
                                                  const int* __restrict__ eval_from,
                                                  const int* __restrict__ u_type,
                                                  int* __restrict__ len_in,
                                                  int* __restrict__ inp,
                                                  float* __restrict__ out) {
  int n = blockIdx.x;          // session
  int lane = threadIdx.x;      // 0..63
  int b = n >> 5, s = n & 31;
  int allow = (s >= eval_from[b]) ? 1 : 0;
  int id = item_id[n * NI + lane];
  if (id < 0) id = 0;
  id *= allow;
  unsigned long long m = __ballot(id != 0);
  int length = __popcll(m);
  int li = length - 1;
  int tv = __shfl(id, (length > 0) ? (length - 1) : 0, 64);
  int target = (length > 0) ? tv : 0;
  if (lane < LL) inp[n * LL + lane] = (lane < li) ? id : 0;
  if (lane == 0) {
    len_in[n] = li;
    out[NSESS * 256 + n] = (float)target;            // Output 1: target
    out[NSESS * 256 + NSESS + n] = (float)u_type[b]; // Output 2: u
  }
}

// ---------------- K2: weights -> bf16 ----------------
__global__ __launch_bounds__(256) void cvt_weights(const float* __restrict__ W_ih,
                                                   const float* __restrict__ W_hh,
                                                   const float* __restrict__ W_a1,
                                                   unsigned short* __restrict__ Wb,
                                                   unsigned short* __restrict__ Whs,
                                                   unsigned short* __restrict__ Wa1b) {
  int i = blockIdx.x * 256 + threadIdx.x;   // 98304 threads
  Wb[i] = f2b(W_ih[i]);
  if (i < GG * HH) Whs[i] = f2b(W_hh[i]);   // W_hh bf16 [384][128]
  if (i < HH * HH) Wa1b[i] = f2b(W_a1[i]);  // W_a1 bf16 [N][K]
}

// ---------------- K3: gi = emb[inp] @ W_ih^T + b_ih (shared-staged A) ----------------
// 2016 blocks x 512 thr (8 waves). Wave w owns gate strip w*48 (B in 96 VGPR).
// Block processes 4 M-tiles; A staged to LDS once per tile, shared by 8 waves
// (8x A reuse). 1 LDS-only barrier per tile. gi layout: [l][n][384].
__global__ __launch_bounds__(512, 2) void gemm_in(const float* __restrict__ emb,
                                                  const unsigned short* __restrict__ Wb,
                                                  const float* __restrict__ b_ih,
                                                  const int* __restrict__ inp,
                                                  unsigned short* __restrict__ gi) {
  constexpr int XP = 264;                      // padded row stride (u16)
  __shared__ unsigned short Ash[2][16 * XP];   // 16896 B

  const int t = threadIdx.x;
  const int lane = t & 63, w = t >> 6;
  const int ccol = lane & 15, kg = lane >> 4;
  const int g0 = w * 48;

  short8 bfr[3][8];
#pragma unroll
  for (int nt = 0; nt < 3; ++nt) {
    const unsigned short* wrow = Wb + (long)(g0 + nt * 16 + ccol) * EE + kg * 8;
#pragma unroll
    for (int c = 0; c < 8; ++c) bfr[nt][c] = *(const short8*)(wrow + c * 32);
  }
  float bias[3];
#pragma unroll
  for (int nt = 0; nt < 3; ++nt) bias[nt] = b_ih[g0 + nt * 16 + ccol];

  const int tile0 = blockIdx.x * 4;
  const int srow = t >> 5;            // 0..15 (staging row)
  const int scol = (t & 31) * 8;      // f32 elem offset within row

  {
    long rid = inp[tile0 * 16 + srow];
    const float* x = emb + rid * EE + scol;
    float4 a0 = *(const float4*)x, a1 = *(const float4*)(x + 4);
    short8 v;
    v[0]=(short)f2b(a0.x); v[1]=(short)f2b(a0.y); v[2]=(short)f2b(a0.z); v[3]=(short)f2b(a0.w);
    v[4]=(short)f2b(a1.x); v[5]=(short)f2b(a1.y); v[6]=(short)f2b(a1.z); v[7]=(short)f2b(a1.w);
    *(short8*)(&Ash[0][srow * XP + scol]) = v;
  }
  __syncthreads();

  for (int i = 0; i < 4; ++i) {
    const int cur = i & 1;
    const int m0 = (tile0 + i) * 16;

    float4 a0, a1;
    if (i + 1 < 4) {
      long rid = inp[(tile0 + i + 1) * 16 + srow];
      const float* x = emb + rid * EE + scol;
      a0 = *(const float4*)x; a1 = *(const float4*)(x + 4);
    }

    f32x4 acc[3];
#pragma unroll
    for (int nt = 0; nt < 3; ++nt)
      acc[nt] = (f32x4){bias[nt], bias[nt], bias[nt], bias[nt]};
#pragma unroll
    for (int c = 0; c < 8; ++c) {
      short8 af = *(const short8*)(&Ash[cur][ccol * XP + c * 32 + kg * 8]);
#pragma unroll
      for (int nt = 0; nt < 3; ++nt)
        acc[nt] = __builtin_amdgcn_mfma_f32_16x16x32_bf16(af, bfr[nt][c], acc[nt], 0, 0, 0);
    }

    // store: row m = m0+kg*4+j -> (n = m/63, l = m%63); gi[l][n][g]
    long base[4];
#pragma unroll
    for (int j = 0; j < 4; ++j) {
      int m = m0 + kg * 4 + j;
      int n = m / 63;
      int l = m - 63 * n;
      base[j] = ((long)l * NSESS + n) * GG;
    }
#pragma unroll
    for (int nt = 0; nt < 3; ++nt) {
      int g = g0 + nt * 16 + ccol;
#pragma unroll
      for (int j = 0; j < 4; ++j)
        gi[base[j] + g] = f2b(acc[nt][j]);
    }

    if (i + 1 < 4) {
      short8 v;
      v[0]=(short)f2b(a0.x); v[1]=(short)f2b(a0.y); v[2]=(short)f2b(a0.z); v[3]=(short)f2b(a0.w);
      v[4]=(short)f2b(a1.x); v[5]=(short)f2b(a1.y); v[6]=(short)f2b(a1.z); v[7]=(short)f2b(a1.w);
      *(short8*)(&Ash[cur ^ 1][srow * XP + scol]) = v;
    }
    barrier_lds_only();
  }
}

// ---------------- K4: GRU via MFMA, SWAPPED operands: C[session][gate] ----------------
// 128 WGs x 512 thr, 16 sess/WG. mfma(A=W_hh, B=h): lane owns session=ccol,
// gate positions p0..p0+3. Per step/wave: 4 ds_read_b128 + 3 global b64 gv
// (prefetched 2 deep) + 12 MFMA + gates + 1 ds_write_b64 + 1 global b64 store.
__global__ __launch_bounds__(512) void gru_mfma(const unsigned short* __restrict__ Whs,
                                                const float* __restrict__ b_hh,
                                                const unsigned short* __restrict__ gi,
                                                const int* __restrict__ len_in,
                                                unsigned short* __restrict__ outs,
                                                float* __restrict__ ht,
                                                float* __restrict__ out) {
  __shared__ unsigned short ring[2 * 2048];   // 8192 B: [slot][16 sess][128] swz16B

  const int t = threadIdx.x;
  const int w = t >> 6, lane = t & 63;
  const int ccol = lane & 15, kg = lane >> 4;
  const int n0 = blockIdx.x * 16;
  const int jh = w * 16 + ccol;     // A-frag row (gate within cls)
  const int p0 = w * 16 + kg * 4;   // this lane's 4 gate positions (C rows)
  const int swz = (ccol & 7) << 3;  // u16-unit XOR key

  short8 bfr[3][4];
#pragma unroll
  for (int cls = 0; cls < 3; ++cls) {
    const unsigned short* wrow = Whs + (long)(cls * HH + jh) * HH;
#pragma unroll
    for (int c = 0; c < 4; ++c)
      bfr[cls][c] = *(const short8*)(wrow + c * 32 + kg * 8);
  }
  f32x4 bhv[3];
#pragma unroll
  for (int cls = 0; cls < 3; ++cls)
    bhv[cls] = *(const f32x4*)(b_hh + cls * HH + p0);

  const int li = len_in[n0 + ccol];
  float hold[4] = {0.f, 0.f, 0.f, 0.f};

  for (int idx = t; idx < 2 * 2048; idx += 512) ring[idx] = 0;

  const unsigned short* gbase = gi + (long)(n0 + ccol) * GG + p0;
  const long lstride = (long)NSESS * GG;
#define GA(l, cls) ((const uint2*)(gbase + (long)(l) * lstride + (cls) * HH))

  uint2 gA[3], gB[3];
#pragma unroll
  for (int cls = 0; cls < 3; ++cls) gA[cls] = *GA(0, cls);
#pragma unroll
  for (int cls = 0; cls < 3; ++cls) gB[cls] = *GA(1, cls);

  barrier_lds_only();

  auto step = [&](int l, uint2 (&gbuf)[3]) {
    float gvv[3][4];
#pragma unroll
    for (int cls = 0; cls < 3; ++cls) {
      gvv[cls][0] = lo16(gbuf[cls].x); gvv[cls][1] = hi16(gbuf[cls].x);
      gvv[cls][2] = lo16(gbuf[cls].y); gvv[cls][3] = hi16(gbuf[cls].y);
    }
    if (l + 2 < LL) {
#pragma unroll
      for (int cls = 0; cls < 3; ++cls) gbuf[cls] = *GA(l + 2, cls);
    }

    const unsigned short* rb = ring + ((l + 1) & 1) * 2048 + ccol * HH;
    short8 hf[4];
#pragma unroll
    for (int c = 0; c < 4; ++c)
      hf[c] = *(const short8*)(rb + ((c * 32 + kg * 8) ^ swz));

    f32x4 acc[3];
#pragma unroll
    for (int cls = 0; cls < 3; ++cls) {
      acc[cls] = bhv[cls];
#pragma unroll
      for (int c = 0; c < 4; ++c)
        acc[cls] = __builtin_amdgcn_mfma_f32_16x16x32_bf16(bfr[cls][c], hf[c], acc[cls], 0, 0, 0);
    }

    bool valid = (l < li);
#pragma unroll
    for (int j = 0; j < 4; ++j) {
      float rg = sigmoidf_(gvv[0][j] + acc[0][j]);
      float zg = sigmoidf_(gvv[1][j] + acc[1][j]);
      float ng = tanh2_(gvv[2][j] + rg * acc[2][j]);
      float hnew = ng + zg * (hold[j] - ng);
      hold[j] = valid ? hnew : hold[j];
    }
    uint2 hp;
    hp.x = (unsigned)f2b(hold[0]) | ((unsigned)f2b(hold[1]) << 16);
    hp.y = (unsigned)f2b(hold[2]) | ((unsigned)f2b(hold[3]) << 16);
    *(uint2*)(ring + (l & 1) * 2048 + ccol * HH + (p0 ^ swz)) = hp;
    uint2 ov = valid ? hp : (uint2){0u, 0u};
    *(uint2*)(outs + ((long)(n0 + ccol) * LL + l) * HH + p0) = ov;
    barrier_lds_only();
  };

  for (int b2 = 0; b2 < 31; ++b2) {
    step(2 * b2, gA);
    step(2 * b2 + 1, gB);
  }
  step(62, gA);
#undef GA

  f32x4 hv = {hold[0], hold[1], hold[2], hold[3]};
  *(f32x4*)(ht + (long)(n0 + ccol) * HH + p0) = hv;
  *(f32x4*)(out + (long)(n0 + ccol) * 256 + HH + p0) = hv;
}

// ---------------- K5: attention via MFMA (256 thr, 4 waves) ----------------
__global__ __launch_bounds__(256) void attn(const unsigned short* __restrict__ outs,
                                            const float* __restrict__ ht,
                                            const unsigned short* __restrict__ Wa1b,
                                            const float* __restrict__ W_a2,
                                            const float* __restrict__ W_vt,
                                            const int* __restrict__ len_in,
                                            float* __restrict__ out) {
  constexpr int OP = HH + 8;               // padded row stride (u16)
  __shared__ unsigned short o_l[64 * OP];  // 17408 B
  __shared__ float q2s[HH];
  __shared__ float wvt[HH];
  __shared__ float hts[HH];
  __shared__ float aw[4][64];              // per-wave alpha partials
  __shared__ float alphas[64];

  const int n = blockIdx.x;
  const int t = threadIdx.x;
  const int lane = t & 63, wv = t >> 6;
  const int ccol = lane & 15, kg = lane >> 4;
  const int li = len_in[n];

  const unsigned* src = (const unsigned*)(outs + (long)n * LL * HH);
  for (int idx = t; idx < LL * 64; idx += 256) {
    int r = idx >> 6, c2 = idx & 63;
    ((unsigned*)(o_l + r * OP))[c2] = src[r * 64 + c2];
  }
  if (t < 64) ((unsigned*)(o_l + 63 * OP))[t] = 0;
  if (t < HH) { hts[t] = ht[(long)n * HH + t]; wvt[t] = W_vt[t]; }

  short8 bfr[2][4];
#pragma unroll
  for (int nt = 0; nt < 2; ++nt) {
    int G = wv * 32 + nt * 16 + ccol;
#pragma unroll
    for (int c = 0; c < 4; ++c)
      bfr[nt][c] = *(const short8*)(Wa1b + (long)G * HH + c * 32 + kg * 8);
  }
  __syncthreads();

  if (t < HH) {
    float a = 0.f;
    const float* w2 = W_a2 + t * HH;
    for (int k = 0; k < HH; ++k) a += hts[k] * w2[k];
    q2s[t] = a;
  }
  __syncthreads();

  f32x4 acc[4][2];
#pragma unroll
  for (int mt = 0; mt < 4; ++mt)
#pragma unroll
    for (int nt = 0; nt < 2; ++nt) acc[mt][nt] = (f32x4){0.f, 0.f, 0.f, 0.f};
#pragma unroll
  for (int mt = 0; mt < 4; ++mt) {
#pragma unroll
    for (int c = 0; c < 4; ++c) {
      short8 af = *(const short8*)(o_l + (mt * 16 + ccol) * OP + c * 32 + kg * 8);
#pragma unroll
      for (int nt = 0; nt < 2; ++nt)
        acc[mt][nt] = __builtin_amdgcn_mfma_f32_16x16x32_bf16(af, bfr[nt][c], acc[mt][nt], 0, 0, 0);
    }
  }

  float q2v[2], wvv[2];
#pragma unroll
  for (int nt = 0; nt < 2; ++nt) {
    int cg = wv * 32 + nt * 16 + ccol;
    q2v[nt] = q2s[cg]; wvv[nt] = wvt[cg];
  }
#pragma unroll
  for (int mt = 0; mt < 4; ++mt) {
    float part[4] = {0.f, 0.f, 0.f, 0.f};
#pragma unroll
    for (int nt = 0; nt < 2; ++nt)
#pragma unroll
      for (int j = 0; j < 4; ++j)
        part[j] += sigmoidf_(acc[mt][nt][j] + q2v[nt]) * wvv[nt];
#pragma unroll
    for (int j = 0; j < 4; ++j) {
#pragma unroll
      for (int off = 1; off < 16; off <<= 1)
        part[j] += __shfl_xor(part[j], off, 64);
    }
    if (ccol == 0) {
#pragma unroll
      for (int j = 0; j < 4; ++j) aw[wv][mt * 16 + kg * 4 + j] = part[j];
    }
  }
  __syncthreads();

  if (t < 64) {
    float s = aw[0][t] + aw[1][t] + aw[2][t] + aw[3][t];
    alphas[t] = (t < li) ? s : 0.f;
  }
  __syncthreads();

  if (t < HH) {
    float c = 0.f;
    for (int l = 0; l < LL; ++l) c = fmaf(alphas[l], b2f(o_l[l * OP + t]), c);
    out[(long)n * 256 + t] = c;
  }
}

extern "C" void kernel_launch(void* const* d_in, const int* in_sizes, int n_in,
                              void* d_out, int out_size, void* d_ws, size_t ws_size,
                              hipStream_t stream) {
  (void)in_sizes; (void)n_in; (void)out_size; (void)ws_size;
  const int* item_id   = (const int*)d_in[0];
  const int* eval_from = (const int*)d_in[1];
  const int* u_type    = (const int*)d_in[2];
  const float* emb     = (const float*)d_in[3];
  const float* W_ih    = (const float*)d_in[4];
  const float* W_hh    = (const float*)d_in[5];
  const float* b_ih    = (const float*)d_in[6];
  const float* b_hh    = (const float*)d_in[7];
  const float* W_a1    = (const float*)d_in[8];
  const float* W_a2    = (const float*)d_in[9];
  const float* W_vt    = (const float*)d_in[10];

  float* out = (float*)d_out;   // f32: reps[2048*256] | target[2048] | u[2048]
  char* ws = (char*)d_ws;
  int* len_in           = (int*)(ws + 0);                      //      8192 B
  int* inp              = (int*)(ws + 8192);                   //    516096 B
  unsigned short* Wb    = (unsigned short*)(ws + 524288);      //    196608 B
  unsigned short* Whs   = (unsigned short*)(ws + 720896);      //     98304 B
  float* ht             = (float*)(ws + 819200);               //   1048576 B
  unsigned short* gi    = (unsigned short*)(ws + 1867776);     //  99090432 B  [l][n][384]
  unsigned short* outs  = (unsigned short*)(ws + 100958208);   //  33030144 B -> ends 133988352
  unsigned short* Wa1b  = (unsigned short*)(ws + 133988352);   //     32768 B -> ends 134021120

  prep_kernel<<<NSESS, 64, 0, stream>>>(item_id, eval_from, u_type, len_in, inp, out);
  cvt_weights<<<384, 256, 0, stream>>>(W_ih, W_hh, W_a1, Wb, Whs, Wa1b);
  gemm_in<<<2016, 512, 0, stream>>>(emb, Wb, b_ih, inp, gi);
  gru_mfma<<<NSESS / 16, 512, 0, stream>>>(Whs, b_hh, gi, len_in, outs, ht, out);
  attn<<<NSESS, 256, 0, stream>>>(outs, ht, Wa1b, W_a2, W_vt, len_in, out);
}

// Round 22
// 174.639 us; speedup vs baseline: 1.4051x; 1.1317x over previous
//
#include <hip/hip_runtime.h>
#include <hip/hip_bf16.h>

#define NSESS 2048
#define NI 64      // I
#define LL 63      // L = I-1
#define EE 256
#define HH 128
#define GG 384     // 3H

typedef __attribute__((ext_vector_type(8))) short short8;
typedef __attribute__((ext_vector_type(4))) float f32x4;

static __device__ __forceinline__ unsigned short f2b(float f) {
  union { float f; unsigned u; } v; v.f = f;
  unsigned r = (v.u + 0x7FFFu + ((v.u >> 16) & 1u)) >> 16;
  return (unsigned short)r;
}
static __device__ __forceinline__ float b2f(unsigned short s) {
  union { unsigned u; float f; } v; v.u = ((unsigned)s) << 16;
  return v.f;
}
static __device__ __forceinline__ float lo16(unsigned u) {
  union { unsigned v; float f; } x; x.v = u << 16; return x.f;
}
static __device__ __forceinline__ float hi16(unsigned u) {
  union { unsigned v; float f; } x; x.v = u & 0xFFFF0000u; return x.f;
}
static __device__ __forceinline__ float sigmoidf_(float x) {
  return 1.f / (1.f + __expf(-x));
}
static __device__ __forceinline__ float tanh2_(float y) {
  float e = __expf(2.f * y);            // inf-safe
  return 1.f - 2.f / (1.f + e);
}
// LDS-only barrier: waits ds ops, does NOT drain vmcnt.
static __device__ __forceinline__ void barrier_lds_only() {
  asm volatile("s_waitcnt lgkmcnt(0)" ::: "memory");
  __builtin_amdgcn_sched_barrier(0);
  __builtin_amdgcn_s_barrier();
  __builtin_amdgcn_sched_barrier(0);
}

// ---------------- K1: per-session prep ----------------
__global__ __launch_bounds__(64) void prep_kernel(const int* __restrict__ item_id,
                                                  const int* __restrict__ eval_from,
                                                  const int* __restrict__ u_type,
                                                  int* __restrict__ len_in,
                                                  int* __restrict__ inp,
                                                  float* __restrict__ out) {
  int n = blockIdx.x;          // session
  int lane = threadIdx.x;      // 0..63
  int b = n >> 5, s = n & 31;
  int allow = (s >= eval_from[b]) ? 1 : 0;
  int id = item_id[n * NI + lane];
  if (id < 0) id = 0;
  id *= allow;
  unsigned long long m = __ballot(id != 0);
  int length = __popcll(m);
  int li = length - 1;
  int tv = __shfl(id, (length > 0) ? (length - 1) : 0, 64);
  int target = (length > 0) ? tv : 0;
  if (lane < LL) inp[n * LL + lane] = (lane < li) ? id : 0;
  if (lane == 0) {
    len_in[n] = li;
    out[NSESS * 256 + n] = (float)target;            // Output 1: target
    out[NSESS * 256 + NSESS + n] = (float)u_type[b]; // Output 2: u
  }
}

// ---------------- K2: weights -> bf16 ----------------
__global__ __launch_bounds__(256) void cvt_weights(const float* __restrict__ W_ih,
                                                   const float* __restrict__ W_hh,
                                                   const float* __restrict__ W_a1,
                                                   unsigned short* __restrict__ Wb,
                                                   unsigned short* __restrict__ Whs,
                                                   unsigned short* __restrict__ Wa1b) {
  int i = blockIdx.x * 256 + threadIdx.x;   // 98304 threads
  Wb[i] = f2b(W_ih[i]);
  if (i < GG * HH) Whs[i] = f2b(W_hh[i]);   // W_hh bf16 [384][128]
  if (i < HH * HH) Wa1b[i] = f2b(W_a1[i]);  // W_a1 bf16 [N][K]
}

// ---------------- K3: gi = emb[inp] @ W_ih^T + b_ih (shared-staged A) ----------------
// 504 blocks x 512 thr (8 waves). Wave w owns gate strip w*48 (B in 96 VGPR).
// Block processes 16 M-tiles; A staged to LDS once per tile (8x reuse), 1 LDS
// barrier per tile. Stores masked by l < len_in[n] (padded gi never consumed).
__global__ __launch_bounds__(512, 2) void gemm_in(const float* __restrict__ emb,
                                                  const unsigned short* __restrict__ Wb,
                                                  const float* __restrict__ b_ih,
                                                  const int* __restrict__ inp,
                                                  const int* __restrict__ len_in,
                                                  unsigned short* __restrict__ gi) {
  constexpr int XP = 264;                      // padded row stride (u16)
  __shared__ unsigned short Ash[2][16 * XP];   // 16896 B

  const int t = threadIdx.x;
  const int lane = t & 63, w = t >> 6;
  const int ccol = lane & 15, kg = lane >> 4;
  const int g0 = w * 48;

  short8 bfr[3][8];
#pragma unroll
  for (int nt = 0; nt < 3; ++nt) {
    const unsigned short* wrow = Wb + (long)(g0 + nt * 16 + ccol) * EE + kg * 8;
#pragma unroll
    for (int c = 0; c < 8; ++c) bfr[nt][c] = *(const short8*)(wrow + c * 32);
  }
  float bias[3];
#pragma unroll
  for (int nt = 0; nt < 3; ++nt) bias[nt] = b_ih[g0 + nt * 16 + ccol];

  const int tile0 = blockIdx.x * 16;
  const int srow = t >> 5;            // 0..15 (staging row)
  const int scol = (t & 31) * 8;      // f32 elem offset within row

  {
    long rid = inp[tile0 * 16 + srow];
    const float* x = emb + rid * EE + scol;
    float4 a0 = *(const float4*)x, a1 = *(const float4*)(x + 4);
    short8 v;
    v[0]=(short)f2b(a0.x); v[1]=(short)f2b(a0.y); v[2]=(short)f2b(a0.z); v[3]=(short)f2b(a0.w);
    v[4]=(short)f2b(a1.x); v[5]=(short)f2b(a1.y); v[6]=(short)f2b(a1.z); v[7]=(short)f2b(a1.w);
    *(short8*)(&Ash[0][srow * XP + scol]) = v;
  }
  __syncthreads();

  for (int i = 0; i < 16; ++i) {
    const int cur = i & 1;
    const int m0 = (tile0 + i) * 16;

    float4 a0, a1;
    if (i + 1 < 16) {
      long rid = inp[(tile0 + i + 1) * 16 + srow];
      const float* x = emb + rid * EE + scol;
      a0 = *(const float4*)x; a1 = *(const float4*)(x + 4);
    }

    f32x4 acc[3];
#pragma unroll
    for (int nt = 0; nt < 3; ++nt)
      acc[nt] = (f32x4){bias[nt], bias[nt], bias[nt], bias[nt]};
#pragma unroll
    for (int c = 0; c < 8; ++c) {
      short8 af = *(const short8*)(&Ash[cur][ccol * XP + c * 32 + kg * 8]);
#pragma unroll
      for (int nt = 0; nt < 3; ++nt)
        acc[nt] = __builtin_amdgcn_mfma_f32_16x16x32_bf16(af, bfr[nt][c], acc[nt], 0, 0, 0);
    }

    // store: row m = m0+kg*4+j -> (n = m/63, l = m%63); gi[l][n][g]; mask l<len
    long base[4];
    bool keep[4];
#pragma unroll
    for (int j = 0; j < 4; ++j) {
      int m = m0 + kg * 4 + j;
      int n = m / 63;
      int l = m - 63 * n;
      base[j] = ((long)l * NSESS + n) * GG;
      keep[j] = (l < len_in[n]);
    }
#pragma unroll
    for (int nt = 0; nt < 3; ++nt) {
      int g = g0 + nt * 16 + ccol;
#pragma unroll
      for (int j = 0; j < 4; ++j)
        if (keep[j]) gi[base[j] + g] = f2b(acc[nt][j]);
    }

    if (i + 1 < 16) {
      short8 v;
      v[0]=(short)f2b(a0.x); v[1]=(short)f2b(a0.y); v[2]=(short)f2b(a0.z); v[3]=(short)f2b(a0.w);
      v[4]=(short)f2b(a1.x); v[5]=(short)f2b(a1.y); v[6]=(short)f2b(a1.z); v[7]=(short)f2b(a1.w);
      *(short8*)(&Ash[cur ^ 1][srow * XP + scol]) = v;
    }
    barrier_lds_only();
  }
}

// ---------------- K4: GRU via MFMA, SWAPPED operands: C[session][gate] ----------------
// 128 WGs x 512 thr, 16 sess/WG. mfma(A=W_hh, B=h): lane owns session=ccol,
// gate positions p0..p0+3. Per step/wave: 4 ds_read_b128 + <=3 global b64 gv
// (prefetched 2 deep, li-guarded) + 12 MFMA + gates + 1 ds_write_b64 +
// valid-masked global b64 outs store + 1 barrier.
__global__ __launch_bounds__(512) void gru_mfma(const unsigned short* __restrict__ Whs,
                                                const float* __restrict__ b_hh,
                                                const unsigned short* __restrict__ gi,
                                                const int* __restrict__ len_in,
                                                unsigned short* __restrict__ outs,
                                                float* __restrict__ ht,
                                                float* __restrict__ out) {
  __shared__ unsigned short ring[2 * 2048];   // 8192 B: [slot][16 sess][128] swz16B

  const int t = threadIdx.x;
  const int w = t >> 6, lane = t & 63;
  const int ccol = lane & 15, kg = lane >> 4;
  const int n0 = blockIdx.x * 16;
  const int jh = w * 16 + ccol;     // A-frag row (gate within cls)
  const int p0 = w * 16 + kg * 4;   // this lane's 4 gate positions (C rows)
  const int swz = (ccol & 7) << 3;  // u16-unit XOR key

  short8 bfr[3][4];
#pragma unroll
  for (int cls = 0; cls < 3; ++cls) {
    const unsigned short* wrow = Whs + (long)(cls * HH + jh) * HH;
#pragma unroll
    for (int c = 0; c < 4; ++c)
      bfr[cls][c] = *(const short8*)(wrow + c * 32 + kg * 8);
  }
  f32x4 bhv[3];
#pragma unroll
  for (int cls = 0; cls < 3; ++cls)
    bhv[cls] = *(const f32x4*)(b_hh + cls * HH + p0);

  const int li = len_in[n0 + ccol];
  float hold[4] = {0.f, 0.f, 0.f, 0.f};

  for (int idx = t; idx < 2 * 2048; idx += 512) ring[idx] = 0;

  const unsigned short* gbase = gi + (long)(n0 + ccol) * GG + p0;
  const long lstride = (long)NSESS * GG;
#define GA(l, cls) ((const uint2*)(gbase + (long)(l) * lstride + (cls) * HH))

  uint2 gA[3], gB[3];
#pragma unroll
  for (int cls = 0; cls < 3; ++cls) gA[cls] = *GA(0, cls);
  if (1 < li) {
#pragma unroll
    for (int cls = 0; cls < 3; ++cls) gB[cls] = *GA(1, cls);
  }

  barrier_lds_only();

  auto step = [&](int l, uint2 (&gbuf)[3]) {
    float gvv[3][4];
#pragma unroll
    for (int cls = 0; cls < 3; ++cls) {
      gvv[cls][0] = lo16(gbuf[cls].x); gvv[cls][1] = hi16(gbuf[cls].x);
      gvv[cls][2] = lo16(gbuf[cls].y); gvv[cls][3] = hi16(gbuf[cls].y);
    }
    // prefetch l+2 only if that step will actually be consumed (l+2 < li)
    if (l + 2 < LL && l + 2 < li) {
#pragma unroll
      for (int cls = 0; cls < 3; ++cls) gbuf[cls] = *GA(l + 2, cls);
    }

    const unsigned short* rb = ring + ((l + 1) & 1) * 2048 + ccol * HH;
    short8 hf[4];
#pragma unroll
    for (int c = 0; c < 4; ++c)
      hf[c] = *(const short8*)(rb + ((c * 32 + kg * 8) ^ swz));

    f32x4 acc[3];
#pragma unroll
    for (int cls = 0; cls < 3; ++cls) {
      acc[cls] = bhv[cls];
#pragma unroll
      for (int c = 0; c < 4; ++c)
        acc[cls] = __builtin_amdgcn_mfma_f32_16x16x32_bf16(bfr[cls][c], hf[c], acc[cls], 0, 0, 0);
    }

    bool valid = (l < li);
#pragma unroll
    for (int j = 0; j < 4; ++j) {
      float rg = sigmoidf_(gvv[0][j] + acc[0][j]);
      float zg = sigmoidf_(gvv[1][j] + acc[1][j]);
      float ng = tanh2_(gvv[2][j] + rg * acc[2][j]);
      float hnew = ng + zg * (hold[j] - ng);
      hold[j] = valid ? hnew : hold[j];
    }
    uint2 hp;
    hp.x = (unsigned)f2b(hold[0]) | ((unsigned)f2b(hold[1]) << 16);
    hp.y = (unsigned)f2b(hold[2]) | ((unsigned)f2b(hold[3]) << 16);
    *(uint2*)(ring + (l & 1) * 2048 + ccol * HH + (p0 ^ swz)) = hp;
    if (valid)
      *(uint2*)(outs + ((long)(n0 + ccol) * LL + l) * HH + p0) = hp;
    barrier_lds_only();
  };

  for (int b2 = 0; b2 < 31; ++b2) {
    step(2 * b2, gA);
    step(2 * b2 + 1, gB);
  }
  step(62, gA);
#undef GA

  f32x4 hv = {hold[0], hold[1], hold[2], hold[3]};
  *(f32x4*)(ht + (long)(n0 + ccol) * HH + p0) = hv;
  *(f32x4*)(out + (long)(n0 + ccol) * 256 + HH + p0) = hv;
}

// ---------------- K5: attention via MFMA (256 thr, 4 waves) ----------------
// Padded-step o_l rows may hold stale/poison values; every use is masked by
// alphas (zeroed for l >= li), and poison/stale data is finite -> safe.
__global__ __launch_bounds__(256) void attn(const unsigned short* __restrict__ outs,
                                            const float* __restrict__ ht,
                                            const unsigned short* __restrict__ Wa1b,
                                            const float* __restrict__ W_a2,
                                            const float* __restrict__ W_vt,
                                            const int* __restrict__ len_in,
                                            float* __restrict__ out) {
  constexpr int OP = HH + 8;               // padded row stride (u16)
  __shared__ unsigned short o_l[64 * OP];  // 17408 B
  __shared__ float q2s[HH];
  __shared__ float wvt[HH];
  __shared__ float hts[HH];
  __shared__ float aw[4][64];              // per-wave alpha partials
  __shared__ float alphas[64];

  const int n = blockIdx.x;
  const int t = threadIdx.x;
  const int lane = t & 63, wv = t >> 6;
  const int ccol = lane & 15, kg = lane >> 4;
  const int li = len_in[n];

  const unsigned* src = (const unsigned*)(outs + (long)n * LL * HH);
  for (int idx = t; idx < LL * 64; idx += 256) {
    int r = idx >> 6, c2 = idx & 63;
    ((unsigned*)(o_l + r * OP))[c2] = src[r * 64 + c2];
  }
  if (t < 64) ((unsigned*)(o_l + 63 * OP))[t] = 0;
  if (t < HH) { hts[t] = ht[(long)n * HH + t]; wvt[t] = W_vt[t]; }

  short8 bfr[2][4];
#pragma unroll
  for (int nt = 0; nt < 2; ++nt) {
    int G = wv * 32 + nt * 16 + ccol;
#pragma unroll
    for (int c = 0; c < 4; ++c)
      bfr[nt][c] = *(const short8*)(Wa1b + (long)G * HH + c * 32 + kg * 8);
  }
  __syncthreads();

  if (t < HH) {
    float a = 0.f;
    const float* w2 = W_a2 + t * HH;
    for (int k = 0; k < HH; ++k) a += hts[k] * w2[k];
    q2s[t] = a;
  }
  __syncthreads();

  f32x4 acc[4][2];
#pragma unroll
  for (int mt = 0; mt < 4; ++mt)
#pragma unroll
    for (int nt = 0; nt < 2; ++nt) acc[mt][nt] = (f32x4){0.f, 0.f, 0.f, 0.f};
#pragma unroll
  for (int mt = 0; mt < 4; ++mt) {
#pragma unroll
    for (int c = 0; c < 4; ++c) {
      short8 af = *(const short8*)(o_l + (mt * 16 + ccol) * OP + c * 32 + kg * 8);
#pragma unroll
      for (int nt = 0; nt < 2; ++nt)
        acc[mt][nt] = __builtin_amdgcn_mfma_f32_16x16x32_bf16(af, bfr[nt][c], acc[mt][nt], 0, 0, 0);
    }
  }

  float q2v[2], wvv[2];
#pragma unroll
  for (int nt = 0; nt < 2; ++nt) {
    int cg = wv * 32 + nt * 16 + ccol;
    q2v[nt] = q2s[cg]; wvv[nt] = wvt[cg];
  }
#pragma unroll
  for (int mt = 0; mt < 4; ++mt) {
    float part[4] = {0.f, 0.f, 0.f, 0.f};
#pragma unroll
    for (int nt = 0; nt < 2; ++nt)
#pragma unroll
      for (int j = 0; j < 4; ++j)
        part[j] += sigmoidf_(acc[mt][nt][j] + q2v[nt]) * wvv[nt];
#pragma unroll
    for (int j = 0; j < 4; ++j) {
#pragma unroll
      for (int off = 1; off < 16; off <<= 1)
        part[j] += __shfl_xor(part[j], off, 64);
    }
    if (ccol == 0) {
#pragma unroll
      for (int j = 0; j < 4; ++j) aw[wv][mt * 16 + kg * 4 + j] = part[j];
    }
  }
  __syncthreads();

  if (t < 64) {
    float s = aw[0][t] + aw[1][t] + aw[2][t] + aw[3][t];
    alphas[t] = (t < li) ? s : 0.f;
  }
  __syncthreads();

  if (t < HH) {
    float c = 0.f;
    for (int l = 0; l < LL; ++l) c = fmaf(alphas[l], b2f(o_l[l * OP + t]), c);
    out[(long)n * 256 + t] = c;
  }
}

extern "C" void kernel_launch(void* const* d_in, const int* in_sizes, int n_in,
                              void* d_out, int out_size, void* d_ws, size_t ws_size,
                              hipStream_t stream) {
  (void)in_sizes; (void)n_in; (void)out_size; (void)ws_size;
  const int* item_id   = (const int*)d_in[0];
  const int* eval_from = (const int*)d_in[1];
  const int* u_type    = (const int*)d_in[2];
  const float* emb     = (const float*)d_in[3];
  const float* W_ih    = (const float*)d_in[4];
  const float* W_hh    = (const float*)d_in[5];
  const float* b_ih    = (const float*)d_in[6];
  const float* b_hh    = (const float*)d_in[7];
  const float* W_a1    = (const float*)d_in[8];
  const float* W_a2    = (const float*)d_in[9];
  const float* W_vt    = (const float*)d_in[10];

  float* out = (float*)d_out;   // f32: reps[2048*256] | target[2048] | u[2048]
  char* ws = (char*)d_ws;
  int* len_in           = (int*)(ws + 0);                      //      8192 B
  int* inp              = (int*)(ws + 8192);                   //    516096 B
  unsigned short* Wb    = (unsigned short*)(ws + 524288);      //    196608 B
  unsigned short* Whs   = (unsigned short*)(ws + 720896);      //     98304 B
  float* ht             = (float*)(ws + 819200);               //   1048576 B
  unsigned short* gi    = (unsigned short*)(ws + 1867776);     //  99090432 B  [l][n][384]
  unsigned short* outs  = (unsigned short*)(ws + 100958208);   //  33030144 B -> ends 133988352
  unsigned short* Wa1b  = (unsigned short*)(ws + 133988352);   //     32768 B -> ends 134021120

  prep_kernel<<<NSESS, 64, 0, stream>>>(item_id, eval_from, u_type, len_in, inp, out);
  cvt_weights<<<384, 256, 0, stream>>>(W_ih, W_hh, W_a1, Wb, Whs, Wa1b);
  gemm_in<<<504, 512, 0, stream>>>(emb, Wb, b_ih, inp, len_in, gi);
  gru_mfma<<<NSESS / 16, 512, 0, stream>>>(Whs, b_hh, gi, len_in, outs, ht, out);
  attn<<<NSESS, 256, 0, stream>>>(outs, ht, Wa1b, W_a2, W_vt, len_in, out);
}

// Round 23
// 171.713 us; speedup vs baseline: 1.4290x; 1.0170x over previous
//
#include <hip/hip_runtime.h>
#include <hip/hip_bf16.h>

#define NSESS 2048
#define NI 64      // I
#define LL 63      // L = I-1
#define EE 256
#define HH 128
#define GG 384     // 3H

typedef __attribute__((ext_vector_type(8))) short short8;
typedef __attribute__((ext_vector_type(4))) float f32x4;

static __device__ __forceinline__ unsigned short f2b(float f) {
  union { float f; unsigned u; } v; v.f = f;
  unsigned r = (v.u + 0x7FFFu + ((v.u >> 16) & 1u)) >> 16;
  return (unsigned short)r;
}
static __device__ __forceinline__ float b2f(unsigned short s) {
  union { unsigned u; float f; } v; v.u = ((unsigned)s) << 16;
  return v.f;
}
static __device__ __forceinline__ float lo16(unsigned u) {
  union { unsigned v; float f; } x; x.v = u << 16; return x.f;
}
static __device__ __forceinline__ float hi16(unsigned u) {
  union { unsigned v; float f; } x; x.v = u & 0xFFFF0000u; return x.f;
}
static __device__ __forceinline__ float sigmoidf_(float x) {
  return 1.f / (1.f + __expf(-x));
}
static __device__ __forceinline__ float tanh2_(float y) {
  float e = __expf(2.f * y);            // inf-safe
  return 1.f - 2.f / (1.f + e);
}
// LDS-only barrier: waits ds ops, does NOT drain vmcnt.
static __device__ __forceinline__ void barrier_lds_only() {
  asm volatile("s_waitcnt lgkmcnt(0)" ::: "memory");
  __builtin_amdgcn_sched_barrier(0);
  __builtin_amdgcn_s_barrier();
  __builtin_amdgcn_sched_barrier(0);
}

// ---------------- K1: per-session prep ----------------
__global__ __launch_bounds__(64) void prep_kernel(const int* __restrict__ item_id,
                                                  const int* __restrict__ eval_from,
                                                  const int* __restrict__ u_type,
                                                  int* __restrict__ len_in,
                                                  int* __restrict__ inp,
                                                  float* __restrict__ out) {
  int n = blockIdx.x;          // session
  int lane = threadIdx.x;      // 0..63
  int b = n >> 5, s = n & 31;
  int allow = (s >= eval_from[b]) ? 1 : 0;
  int id = item_id[n * NI + lane];
  if (id < 0) id = 0;
  id *= allow;
  unsigned long long m = __ballot(id != 0);
  int length = __popcll(m);
  int li = length - 1;
  int tv = __shfl(id, (length > 0) ? (length - 1) : 0, 64);
  int target = (length > 0) ? tv : 0;
  if (lane < LL) inp[n * LL + lane] = (lane < li) ? id : 0;
  if (lane == 0) {
    len_in[n] = li;
    out[NSESS * 256 + n] = (float)target;            // Output 1: target
    out[NSESS * 256 + NSESS + n] = (float)u_type[b]; // Output 2: u
  }
}

// ---------------- K2: weights -> bf16 ----------------
__global__ __launch_bounds__(256) void cvt_weights(const float* __restrict__ W_ih,
                                                   const float* __restrict__ W_hh,
                                                   const float* __restrict__ W_a1,
                                                   unsigned short* __restrict__ Wb,
                                                   unsigned short* __restrict__ Whs,
                                                   unsigned short* __restrict__ Wa1b) {
  int i = blockIdx.x * 256 + threadIdx.x;   // 98304 threads
  Wb[i] = f2b(W_ih[i]);
  if (i < GG * HH) Whs[i] = f2b(W_hh[i]);   // W_hh bf16 [384][128]
  if (i < HH * HH) Wa1b[i] = f2b(W_a1[i]);  // W_a1 bf16 [N][K]
}

// ---------------- K3: gi = emb[inp] @ W_ih^T + b_ih (shared-staged A) ----------------
// 504 blocks x 512 thr (8 waves). Wave w owns gate strip w*48 (B in 96 VGPR).
// Block processes 16 M-tiles; A staged to LDS once per tile (8x reuse), 1 LDS
// barrier per tile. Stores masked by l < len_in[n] (padded gi never consumed).
__global__ __launch_bounds__(512, 2) void gemm_in(const float* __restrict__ emb,
                                                  const unsigned short* __restrict__ Wb,
                                                  const float* __restrict__ b_ih,
                                                  const int* __restrict__ inp,
                                                  const int* __restrict__ len_in,
                                                  unsigned short* __restrict__ gi) {
  constexpr int XP = 264;                      // padded row stride (u16)
  __shared__ unsigned short Ash[2][16 * XP];   // 16896 B

  const int t = threadIdx.x;
  const int lane = t & 63, w = t >> 6;
  const int ccol = lane & 15, kg = lane >> 4;
  const int g0 = w * 48;

  short8 bfr[3][8];
#pragma unroll
  for (int nt = 0; nt < 3; ++nt) {
    const unsigned short* wrow = Wb + (long)(g0 + nt * 16 + ccol) * EE + kg * 8;
#pragma unroll
    for (int c = 0; c < 8; ++c) bfr[nt][c] = *(const short8*)(wrow + c * 32);
  }
  float bias[3];
#pragma unroll
  for (int nt = 0; nt < 3; ++nt) bias[nt] = b_ih[g0 + nt * 16 + ccol];

  const int tile0 = blockIdx.x * 16;
  const int srow = t >> 5;            // 0..15 (staging row)
  const int scol = (t & 31) * 8;      // f32 elem offset within row

  {
    long rid = inp[tile0 * 16 + srow];
    const float* x = emb + rid * EE + scol;
    float4 a0 = *(const float4*)x, a1 = *(const float4*)(x + 4);
    short8 v;
    v[0]=(short)f2b(a0.x); v[1]=(short)f2b(a0.y); v[2]=(short)f2b(a0.z); v[3]=(short)f2b(a0.w);
    v[4]=(short)f2b(a1.x); v[5]=(short)f2b(a1.y); v[6]=(short)f2b(a1.z); v[7]=(short)f2b(a1.w);
    *(short8*)(&Ash[0][srow * XP + scol]) = v;
  }
  __syncthreads();

  for (int i = 0; i < 16; ++i) {
    const int cur = i & 1;
    const int m0 = (tile0 + i) * 16;

    float4 a0, a1;
    if (i + 1 < 16) {
      long rid = inp[(tile0 + i + 1) * 16 + srow];
      const float* x = emb + rid * EE + scol;
      a0 = *(const float4*)x; a1 = *(const float4*)(x + 4);
    }

    f32x4 acc[3];
#pragma unroll
    for (int nt = 0; nt < 3; ++nt)
      acc[nt] = (f32x4){bias[nt], bias[nt], bias[nt], bias[nt]};
#pragma unroll
    for (int c = 0; c < 8; ++c) {
      short8 af = *(const short8*)(&Ash[cur][ccol * XP + c * 32 + kg * 8]);
#pragma unroll
      for (int nt = 0; nt < 3; ++nt)
        acc[nt] = __builtin_amdgcn_mfma_f32_16x16x32_bf16(af, bfr[nt][c], acc[nt], 0, 0, 0);
    }

    // store: row m = m0+kg*4+j -> (n = m/63, l = m%63); gi[l][n][g]; mask l<len
    long base[4];
    bool keep[4];
#pragma unroll
    for (int j = 0; j < 4; ++j) {
      int m = m0 + kg * 4 + j;
      int n = m / 63;
      int l = m - 63 * n;
      base[j] = ((long)l * NSESS + n) * GG;
      keep[j] = (l < len_in[n]);
    }
#pragma unroll
    for (int nt = 0; nt < 3; ++nt) {
      int g = g0 + nt * 16 + ccol;
#pragma unroll
      for (int j = 0; j < 4; ++j)
        if (keep[j]) gi[base[j] + g] = f2b(acc[nt][j]);
    }

    if (i + 1 < 16) {
      short8 v;
      v[0]=(short)f2b(a0.x); v[1]=(short)f2b(a0.y); v[2]=(short)f2b(a0.z); v[3]=(short)f2b(a0.w);
      v[4]=(short)f2b(a1.x); v[5]=(short)f2b(a1.y); v[6]=(short)f2b(a1.z); v[7]=(short)f2b(a1.w);
      *(short8*)(&Ash[cur ^ 1][srow * XP + scol]) = v;
    }
    barrier_lds_only();
  }
}

// ---------------- K4: GRU via MFMA, SWAPPED operands: C[session][gate] ----------------
// 128 WGs x 512 thr, 16 sess/WG. mfma(A=W_hh, B=h): lane owns session=ccol,
// gate positions p0..p0+3. UNCONDITIONAL 2-deep gi prefetch + unconditional
// stores (round-19 pipeline; divergent guards destroyed it in round 22).
// Padded gi reads return finite poison; results discarded via `valid`.
__global__ __launch_bounds__(512) void gru_mfma(const unsigned short* __restrict__ Whs,
                                                const float* __restrict__ b_hh,
                                                const unsigned short* __restrict__ gi,
                                                const int* __restrict__ len_in,
                                                unsigned short* __restrict__ outs,
                                                float* __restrict__ ht,
                                                float* __restrict__ out) {
  __shared__ unsigned short ring[2 * 2048];   // 8192 B: [slot][16 sess][128] swz16B

  const int t = threadIdx.x;
  const int w = t >> 6, lane = t & 63;
  const int ccol = lane & 15, kg = lane >> 4;
  const int n0 = blockIdx.x * 16;
  const int jh = w * 16 + ccol;     // A-frag row (gate within cls)
  const int p0 = w * 16 + kg * 4;   // this lane's 4 gate positions (C rows)
  const int swz = (ccol & 7) << 3;  // u16-unit XOR key

  short8 bfr[3][4];
#pragma unroll
  for (int cls = 0; cls < 3; ++cls) {
    const unsigned short* wrow = Whs + (long)(cls * HH + jh) * HH;
#pragma unroll
    for (int c = 0; c < 4; ++c)
      bfr[cls][c] = *(const short8*)(wrow + c * 32 + kg * 8);
  }
  f32x4 bhv[3];
#pragma unroll
  for (int cls = 0; cls < 3; ++cls)
    bhv[cls] = *(const f32x4*)(b_hh + cls * HH + p0);

  const int li = len_in[n0 + ccol];
  float hold[4] = {0.f, 0.f, 0.f, 0.f};

  for (int idx = t; idx < 2 * 2048; idx += 512) ring[idx] = 0;

  const unsigned short* gbase = gi + (long)(n0 + ccol) * GG + p0;
  const long lstride = (long)NSESS * GG;
#define GA(l, cls) ((const uint2*)(gbase + (long)(l) * lstride + (cls) * HH))

  uint2 gA[3], gB[3];
#pragma unroll
  for (int cls = 0; cls < 3; ++cls) gA[cls] = *GA(0, cls);
#pragma unroll
  for (int cls = 0; cls < 3; ++cls) gB[cls] = *GA(1, cls);

  barrier_lds_only();

  auto step = [&](int l, uint2 (&gbuf)[3]) {
    float gvv[3][4];
#pragma unroll
    for (int cls = 0; cls < 3; ++cls) {
      gvv[cls][0] = lo16(gbuf[cls].x); gvv[cls][1] = hi16(gbuf[cls].x);
      gvv[cls][2] = lo16(gbuf[cls].y); gvv[cls][3] = hi16(gbuf[cls].y);
    }
    if (l + 2 < LL) {
#pragma unroll
      for (int cls = 0; cls < 3; ++cls) gbuf[cls] = *GA(l + 2, cls);
    }

    const unsigned short* rb = ring + ((l + 1) & 1) * 2048 + ccol * HH;
    short8 hf[4];
#pragma unroll
    for (int c = 0; c < 4; ++c)
      hf[c] = *(const short8*)(rb + ((c * 32 + kg * 8) ^ swz));

    f32x4 acc[3];
#pragma unroll
    for (int cls = 0; cls < 3; ++cls) {
      acc[cls] = bhv[cls];
#pragma unroll
      for (int c = 0; c < 4; ++c)
        acc[cls] = __builtin_amdgcn_mfma_f32_16x16x32_bf16(bfr[cls][c], hf[c], acc[cls], 0, 0, 0);
    }

    bool valid = (l < li);
#pragma unroll
    for (int j = 0; j < 4; ++j) {
      float rg = sigmoidf_(gvv[0][j] + acc[0][j]);
      float zg = sigmoidf_(gvv[1][j] + acc[1][j]);
      float ng = tanh2_(gvv[2][j] + rg * acc[2][j]);
      float hnew = ng + zg * (hold[j] - ng);
      hold[j] = valid ? hnew : hold[j];
    }
    uint2 hp;
    hp.x = (unsigned)f2b(hold[0]) | ((unsigned)f2b(hold[1]) << 16);
    hp.y = (unsigned)f2b(hold[2]) | ((unsigned)f2b(hold[3]) << 16);
    *(uint2*)(ring + (l & 1) * 2048 + ccol * HH + (p0 ^ swz)) = hp;
    uint2 ov = valid ? hp : (uint2){0u, 0u};
    *(uint2*)(outs + ((long)(n0 + ccol) * LL + l) * HH + p0) = ov;
    barrier_lds_only();
  };

  for (int b2 = 0; b2 < 31; ++b2) {
    step(2 * b2, gA);
    step(2 * b2 + 1, gB);
  }
  step(62, gA);
#undef GA

  f32x4 hv = {hold[0], hold[1], hold[2], hold[3]};
  *(f32x4*)(ht + (long)(n0 + ccol) * HH + p0) = hv;
  *(f32x4*)(out + (long)(n0 + ccol) * 256 + HH + p0) = hv;
}

// ---------------- K5: attention via MFMA (256 thr, 4 waves) ----------------
__global__ __launch_bounds__(256) void attn(const unsigned short* __restrict__ outs,
                                            const float* __restrict__ ht,
                                            const unsigned short* __restrict__ Wa1b,
                                            const float* __restrict__ W_a2,
                                            const float* __restrict__ W_vt,
                                            const int* __restrict__ len_in,
                                            float* __restrict__ out) {
  constexpr int OP = HH + 8;               // padded row stride (u16)
  __shared__ unsigned short o_l[64 * OP];  // 17408 B
  __shared__ float q2s[HH];
  __shared__ float wvt[HH];
  __shared__ float hts[HH];
  __shared__ float aw[4][64];              // per-wave alpha partials
  __shared__ float alphas[64];

  const int n = blockIdx.x;
  const int t = threadIdx.x;
  const int lane = t & 63, wv = t >> 6;
  const int ccol = lane & 15, kg = lane >> 4;
  const int li = len_in[n];

  const unsigned* src = (const unsigned*)(outs + (long)n * LL * HH);
  for (int idx = t; idx < LL * 64; idx += 256) {
    int r = idx >> 6, c2 = idx & 63;
    ((unsigned*)(o_l + r * OP))[c2] = src[r * 64 + c2];
  }
  if (t < 64) ((unsigned*)(o_l + 63 * OP))[t] = 0;
  if (t < HH) { hts[t] = ht[(long)n * HH + t]; wvt[t] = W_vt[t]; }

  short8 bfr[2][4];
#pragma unroll
  for (int nt = 0; nt < 2; ++nt) {
    int G = wv * 32 + nt * 16 + ccol;
#pragma unroll
    for (int c = 0; c < 4; ++c)
      bfr[nt][c] = *(const short8*)(Wa1b + (long)G * HH + c * 32 + kg * 8);
  }
  __syncthreads();

  if (t < HH) {
    float a = 0.f;
    const float* w2 = W_a2 + t * HH;
    for (int k = 0; k < HH; ++k) a += hts[k] * w2[k];
    q2s[t] = a;
  }
  __syncthreads();

  f32x4 acc[4][2];
#pragma unroll
  for (int mt = 0; mt < 4; ++mt)
#pragma unroll
    for (int nt = 0; nt < 2; ++nt) acc[mt][nt] = (f32x4){0.f, 0.f, 0.f, 0.f};
#pragma unroll
  for (int mt = 0; mt < 4; ++mt) {
#pragma unroll
    for (int c = 0; c < 4; ++c) {
      short8 af = *(const short8*)(o_l + (mt * 16 + ccol) * OP + c * 32 + kg * 8);
#pragma unroll
      for (int nt = 0; nt < 2; ++nt)
        acc[mt][nt] = __builtin_amdgcn_mfma_f32_16x16x32_bf16(af, bfr[nt][c], acc[mt][nt], 0, 0, 0);
    }
  }

  float q2v[2], wvv[2];
#pragma unroll
  for (int nt = 0; nt < 2; ++nt) {
    int cg = wv * 32 + nt * 16 + ccol;
    q2v[nt] = q2s[cg]; wvv[nt] = wvt[cg];
  }
#pragma unroll
  for (int mt = 0; mt < 4; ++mt) {
    float part[4] = {0.f, 0.f, 0.f, 0.f};
#pragma unroll
    for (int nt = 0; nt < 2; ++nt)
#pragma unroll
      for (int j = 0; j < 4; ++j)
        part[j] += sigmoidf_(acc[mt][nt][j] + q2v[nt]) * wvv[nt];
#pragma unroll
    for (int j = 0; j < 4; ++j) {
#pragma unroll
      for (int off = 1; off < 16; off <<= 1)
        part[j] += __shfl_xor(part[j], off, 64);
    }
    if (ccol == 0) {
#pragma unroll
      for (int j = 0; j < 4; ++j) aw[wv][mt * 16 + kg * 4 + j] = part[j];
    }
  }
  __syncthreads();

  if (t < 64) {
    float s = aw[0][t] + aw[1][t] + aw[2][t] + aw[3][t];
    alphas[t] = (t < li) ? s : 0.f;
  }
  __syncthreads();

  if (t < HH) {
    float c = 0.f;
    for (int l = 0; l < LL; ++l) c = fmaf(alphas[l], b2f(o_l[l * OP + t]), c);
    out[(long)n * 256 + t] = c;
  }
}

extern "C" void kernel_launch(void* const* d_in, const int* in_sizes, int n_in,
                              void* d_out, int out_size, void* d_ws, size_t ws_size,
                              hipStream_t stream) {
  (void)in_sizes; (void)n_in; (void)out_size; (void)ws_size;
  const int* item_id   = (const int*)d_in[0];
  const int* eval_from = (const int*)d_in[1];
  const int* u_type    = (const int*)d_in[2];
  const float* emb     = (const float*)d_in[3];
  const float* W_ih    = (const float*)d_in[4];
  const float* W_hh    = (const float*)d_in[5];
  const float* b_ih    = (const float*)d_in[6];
  const float* b_hh    = (const float*)d_in[7];
  const float* W_a1    = (const float*)d_in[8];
  const float* W_a2    = (const float*)d_in[9];
  const float* W_vt    = (const float*)d_in[10];

  float* out = (float*)d_out;   // f32: reps[2048*256] | target[2048] | u[2048]
  char* ws = (char*)d_ws;
  int* len_in           = (int*)(ws + 0);                      //      8192 B
  int* inp              = (int*)(ws + 8192);                   //    516096 B
  unsigned short* Wb    = (unsigned short*)(ws + 524288);      //    196608 B
  unsigned short* Whs   = (unsigned short*)(ws + 720896);      //     98304 B
  float* ht             = (float*)(ws + 819200);               //   1048576 B
  unsigned short* gi    = (unsigned short*)(ws + 1867776);     //  99090432 B  [l][n][384]
  unsigned short* outs  = (unsigned short*)(ws + 100958208);   //  33030144 B -> ends 133988352
  unsigned short* Wa1b  = (unsigned short*)(ws + 133988352);   //     32768 B -> ends 134021120

  prep_kernel<<<NSESS, 64, 0, stream>>>(item_id, eval_from, u_type, len_in, inp, out);
  cvt_weights<<<384, 256, 0, stream>>>(W_ih, W_hh, W_a1, Wb, Whs, Wa1b);
  gemm_in<<<504, 512, 0, stream>>>(emb, Wb, b_ih, inp, len_in, gi);
  gru_mfma<<<NSESS / 16, 512, 0, stream>>>(Whs, b_hh, gi, len_in, outs, ht, out);
  attn<<<NSESS, 256, 0, stream>>>(outs, ht, Wa1b, W_a2, W_vt, len_in, out);
}